// Round 1
// baseline (124.274 us; speedup 1.0000x reference)
//
#include <hip/hip_runtime.h>
#include <math.h>

// GeodesicPrototypeClassifier: out[n,k] = -(2*atanh(clamp(||mobius_add(-x_n, p_k)||)))^2
// N=16384, K=128, D=64, c=1.
//
// Algebraic collapse: ||a*(-x)+b*p||^2 = a^2*x2 - 2ab*xy + b^2*p2,
// so only x2, p2, xy (one D=64 dot) are needed per pair.

#define N_TOTAL 16384
#define K_PROTO 128
#define D_DIM   64
#define NPB     8   // n-rows per 256-thread block (one 32-lane group per row)

__global__ __launch_bounds__(256, 4) void geodesic_kernel(
    const float* __restrict__ x,
    const float* __restrict__ p,
    float* __restrict__ out)
{
    __shared__ float s_scale[K_PROTO];  // projection scale per prototype
    __shared__ float s_p2[K_PROTO];     // ||p_proj||^2 per prototype

    const int t = threadIdx.x;

    // ---- Prologue: _project_ball scale + p2 for all 128 prototypes ----
    if (t < K_PROTO) {
        const float4* pr = (const float4*)(p + t * D_DIM);
        float s2 = 0.f;
        #pragma unroll
        for (int i = 0; i < D_DIM / 4; ++i) {
            float4 v = pr[i];
            s2 += v.x * v.x + v.y * v.y + v.z * v.z + v.w * v.w;
        }
        float nrm  = fmaxf(sqrtf(s2), 1e-15f);
        float maxnorm = 1.0f - 0.001f;              // (1-BALL_EPS)/sqrt(c), c=1
        float scale = fminf(1.0f, maxnorm / nrm);
        s_scale[t] = scale;
        s_p2[t]    = s2 * scale * scale;
    }
    __syncthreads();

    // ---- Main: each lane computes 4 consecutive k for one n-row ----
    const int lane32 = t & 31;
    const int kbase  = lane32 * 4;
    const int n      = blockIdx.x * NPB + (t >> 5);

    const float4* xr = (const float4*)(x + n * D_DIM);
    const float4* pr0 = (const float4*)(p + (kbase + 0) * D_DIM);
    const float4* pr1 = (const float4*)(p + (kbase + 1) * D_DIM);
    const float4* pr2 = (const float4*)(p + (kbase + 2) * D_DIM);
    const float4* pr3 = (const float4*)(p + (kbase + 3) * D_DIM);

    float xy0 = 0.f, xy1 = 0.f, xy2 = 0.f, xy3 = 0.f, x2 = 0.f;

    #pragma unroll 4
    for (int i = 0; i < D_DIM / 4; ++i) {
        float4 xv = xr[i];
        float4 a0 = pr0[i];
        float4 a1 = pr1[i];
        float4 a2 = pr2[i];
        float4 a3 = pr3[i];
        xy0 += xv.x * a0.x + xv.y * a0.y + xv.z * a0.z + xv.w * a0.w;
        xy1 += xv.x * a1.x + xv.y * a1.y + xv.z * a1.z + xv.w * a1.w;
        xy2 += xv.x * a2.x + xv.y * a2.y + xv.z * a2.z + xv.w * a2.w;
        xy3 += xv.x * a3.x + xv.y * a3.y + xv.z * a3.z + xv.w * a3.w;
        x2  += xv.x * xv.x + xv.y * xv.y + xv.z * xv.z + xv.w * xv.w;
    }

    // scale-fold projection into xy; read p2/scale from LDS
    float sc0 = s_scale[kbase + 0], sc1 = s_scale[kbase + 1];
    float sc2 = s_scale[kbase + 2], sc3 = s_scale[kbase + 3];
    float p20 = s_p2[kbase + 0], p21 = s_p2[kbase + 1];
    float p22 = s_p2[kbase + 2], p23 = s_p2[kbase + 3];
    xy0 *= sc0; xy1 *= sc1; xy2 *= sc2; xy3 *= sc3;

    float4 o;
    float* op = &o.x;
    float xys[4] = {xy0, xy1, xy2, xy3};
    float p2s[4] = {p20, p21, p22, p23};

    #pragma unroll
    for (int j = 0; j < 4; ++j) {
        float xy = xys[j];
        float p2 = p2s[j];
        // c = 1
        float a   = 1.0f - 2.0f * xy + p2;
        float b   = 1.0f - x2;
        float den = fmaxf(1.0f - 2.0f * xy + x2 * p2, 1e-15f);
        float ma2 = fmaxf(a * a * x2 - 2.0f * a * b * xy + b * b * p2, 0.0f)
                    / (den * den);
        float z   = fminf(sqrtf(ma2), 1.0f - 1e-05f);
        // dist = 2*atanh(z) = log((1+z)/(1-z)); out = -dist^2
        float l   = logf((1.0f + z) / (1.0f - z));
        op[j] = -(l * l);
    }

    *(float4*)(out + (size_t)n * K_PROTO + kbase) = o;
}

extern "C" void kernel_launch(void* const* d_in, const int* in_sizes, int n_in,
                              void* d_out, int out_size, void* d_ws, size_t ws_size,
                              hipStream_t stream) {
    const float* x = (const float*)d_in[0];   // (16384, 64) f32
    const float* p = (const float*)d_in[1];   // (128, 64) f32
    float* out = (float*)d_out;               // (16384, 128) f32

    dim3 grid(N_TOTAL / NPB);   // 2048 blocks
    dim3 block(256);
    hipLaunchKernelGGL(geodesic_kernel, grid, block, 0, stream, x, p, out);
}

// Round 2
// 68.700 us; speedup vs baseline: 1.8089x; 1.8089x over previous
//
#include <hip/hip_runtime.h>
#include <math.h>

// GeodesicPrototypeClassifier: out[n,k] = -(2*atanh(clamp(||mobius_add(-x_n,p_k)||)))^2
// N=16384, K=128, D=64, c=1.
// ||num||^2 = a^2*x2 - 2ab*xy + b^2*p2 -> only scalars x2,p2,xy needed per pair.
// Structure: GEMM-like. Block = 64n x 128k tile, 256 threads, thread = 4n x 8k.
// LDS row stride 68 floats (16B aligned, !=0 mod 32) + interleaved row ownership
// (rows tn+16j) -> all main-loop ds_read_b128 are <=2-way bank conflicts (free).

#define K_PROTO 128
#define D_DIM   64
#define BN      64
#define STRIDE  68   // floats per LDS row

__global__ __launch_bounds__(256) void geodesic_kernel(
    const float* __restrict__ x,
    const float* __restrict__ p,
    float* __restrict__ out)
{
    __shared__ __align__(16) float xs[BN * STRIDE];      // ~17.4 KB
    __shared__ __align__(16) float ps[K_PROTO * STRIDE]; // ~34.8 KB
    __shared__ float sx2[BN];
    __shared__ float sp2[K_PROTO];
    __shared__ float ssc[K_PROTO];

    const int t  = threadIdx.x;
    const int n0 = blockIdx.x * BN;

    // ---- stage x tile (64 rows x 64 d), fully coalesced ----
    #pragma unroll
    for (int it = 0; it < 4; ++it) {
        int idx = t + 256 * it;          // 0..1023
        int r   = idx >> 4;              // row 0..63
        int c4  = (idx & 15) << 2;       // col 0..60
        float4 v = *(const float4*)(x + (size_t)(n0 + r) * D_DIM + c4);
        *(float4*)(&xs[r * STRIDE + c4]) = v;
    }
    // ---- stage all of p (128 x 64), fully coalesced ----
    #pragma unroll
    for (int it = 0; it < 8; ++it) {
        int idx = t + 256 * it;          // 0..2047
        int r   = idx >> 4;              // row 0..127
        int c4  = (idx & 15) << 2;
        float4 v = *(const float4*)(p + (size_t)r * D_DIM + c4);
        *(float4*)(&ps[r * STRIDE + c4]) = v;
    }
    __syncthreads();

    // ---- per-row scalars: p2 + projection scale, x2 (once per block) ----
    if (t < K_PROTO) {
        float s2 = 0.f;
        #pragma unroll
        for (int i = 0; i < 16; ++i) {
            float4 v = *(const float4*)(&ps[t * STRIDE + 4 * i]);
            s2 += v.x * v.x + v.y * v.y + v.z * v.z + v.w * v.w;
        }
        float nrm = fmaxf(sqrtf(s2), 1e-15f);
        float sc  = fminf(1.0f, 0.999f / nrm);   // (1-BALL_EPS)/sqrt(c)
        ssc[t] = sc;
        sp2[t] = s2 * sc * sc;
    } else if (t < K_PROTO + BN) {
        int r = t - K_PROTO;
        float s2 = 0.f;
        #pragma unroll
        for (int i = 0; i < 16; ++i) {
            float4 v = *(const float4*)(&xs[r * STRIDE + 4 * i]);
            s2 += v.x * v.x + v.y * v.y + v.z * v.z + v.w * v.w;
        }
        sx2[r] = s2;
    }
    __syncthreads();

    // ---- main loop: 4n x 8k register tile, outer product over d ----
    const int tk = t & 15;   // fast lane dim -> coalesced stores
    const int tn = t >> 4;

    float acc[4][8];
    #pragma unroll
    for (int a = 0; a < 4; ++a)
        #pragma unroll
        for (int b = 0; b < 8; ++b) acc[a][b] = 0.f;

    #pragma unroll 4
    for (int i = 0; i < 16; ++i) {
        float4 xa[4], pa[8];
        #pragma unroll
        for (int jn = 0; jn < 4; ++jn)
            xa[jn] = *(const float4*)(&xs[(tn + 16 * jn) * STRIDE + 4 * i]);
        #pragma unroll
        for (int jk = 0; jk < 8; ++jk)
            pa[jk] = *(const float4*)(&ps[(tk + 16 * jk) * STRIDE + 4 * i]);
        #pragma unroll
        for (int jn = 0; jn < 4; ++jn)
            #pragma unroll
            for (int jk = 0; jk < 8; ++jk) {
                acc[jn][jk] += xa[jn].x * pa[jk].x + xa[jn].y * pa[jk].y
                             + xa[jn].z * pa[jk].z + xa[jn].w * pa[jk].w;
            }
    }

    // ---- epilogue: fold projection scale, Mobius norm, atanh, store ----
    float p2v[8], scv[8];
    #pragma unroll
    for (int jk = 0; jk < 8; ++jk) {
        int k = tk + 16 * jk;
        p2v[jk] = sp2[k];
        scv[jk] = ssc[k];
    }

    #pragma unroll
    for (int jn = 0; jn < 4; ++jn) {
        int n = tn + 16 * jn;
        float x2 = sx2[n];
        float b  = 1.0f - x2;
        float* orow = out + (size_t)(n0 + n) * K_PROTO;
        #pragma unroll
        for (int jk = 0; jk < 8; ++jk) {
            float xy  = acc[jn][jk] * scv[jk];
            float p2  = p2v[jk];
            float a   = 1.0f - 2.0f * xy + p2;
            float den = fmaxf(1.0f - 2.0f * xy + x2 * p2, 1e-15f);
            float num2 = fmaxf(a * a * x2 - 2.0f * a * b * xy + b * b * p2, 0.0f);
            float z   = fminf(__fdividef(sqrtf(num2), den), 1.0f - 1e-05f);
            float l   = __logf(__fdividef(1.0f + z, 1.0f - z));
            orow[tk + 16 * jk] = -(l * l);
        }
    }
}

extern "C" void kernel_launch(void* const* d_in, const int* in_sizes, int n_in,
                              void* d_out, int out_size, void* d_ws, size_t ws_size,
                              hipStream_t stream) {
    const float* x = (const float*)d_in[0];   // (16384, 64) f32
    const float* p = (const float*)d_in[1];   // (128, 64) f32
    float* out = (float*)d_out;               // (16384, 128) f32

    dim3 grid(16384 / BN);   // 256 blocks -> 1 per CU
    dim3 block(256);
    hipLaunchKernelGGL(geodesic_kernel, grid, block, 0, stream, x, p, out);
}